// Round 6
// baseline (351.540 us; speedup 1.0000x reference)
//
#include <hip/hip_runtime.h>
#include <math.h>

#define NPTS 8192
#define NB 2
#define NROWS (NB * NPTS)
#define KNN 16
#define KC 6          // per-lane kept candidates (truncated sorted list)

// Spatial grid: 32^3 cells of width H. 4 grids: P/T x batch. g: P=2b, T=2b+1.
#define GRID 32
#define NCELLS (GRID * GRID * GRID)        // 32768
#define TOTCELLS (4 * NCELLS)              // 131072
#define H 0.35f
#define RLO (-5.6f)
#define INVH (1.0f / H)
#define SCAN_BLOCKS 128
#define SEGCAP 132                          // >= 2*64 segments per row-chunk

// QC co-celled queries share one wave's enumeration stream. Items are
// claim-scheduled (dynamic balance). T-cell items are FUSED: one wave runs
// the P-grid and T-grid kNN for the same queries and emits per-row scalars
// (minrow, sum|knnP-knnT|) -- no 16-wide knn arrays in global.
#define QC 3
#define WLCAP 49152
#define QBLOCKS 2048

__device__ __forceinline__ int cellof(float x) {
  int c = (int)floorf((x - RLO) * INVH);
  return min(max(c, 0), GRID - 1);
}

__device__ __forceinline__ float sqd3(float qx, float qy, float qz, float4 c) {
  float dx = qx - c.x, dy = qy - c.y, dz = qz - c.z;
  return fmaf(dx, dx, fmaf(dy, dy, dz * dz));
}

__device__ __forceinline__ int lanerank(unsigned long long mk) {
  return __builtin_amdgcn_mbcnt_hi((unsigned)(mk >> 32),
                                   __builtin_amdgcn_mbcnt_lo((unsigned)mk, 0));
}

// Guarded insert into ascending sorted-K list (per-lane).
template <int K>
__device__ __forceinline__ void insertK(float (&a)[K], float d) {
  if (d < a[K - 1]) {
    a[K - 1] = d;
#pragma unroll
    for (int k = K - 1; k > 0; --k) {
      float lo = fminf(a[k - 1], a[k]);
      a[k] = fmaxf(a[k - 1], a[k]);
      a[k - 1] = lo;
    }
  }
}

// Full ascending bitonic sort of one value per lane across the 64-lane wave.
__device__ __forceinline__ float bitonic_sort64(float v, int lane) {
#pragma unroll
  for (int k = 2; k <= 64; k <<= 1) {
#pragma unroll
    for (int j = k >> 1; j >= 1; j >>= 1) {
      float o = __shfl_xor(v, j, 64);
      bool up = ((lane & k) == 0);
      bool lower = ((lane & j) == 0);
      float mn = fminf(v, o), mx = fmaxf(v, o);
      v = (up == lower) ? mn : mx;
    }
  }
  return v;
}

// Wave-cooperative kNN for QC co-celled queries (R0 enumeration structure:
// streaming candidates from global, expanding Chebyshev shells on the
// counting-sorted grid). Exactness per query q: after completing shell m, an
// unvisited point is > (m*H + fq[q]) away (fq = min per-axis in-cell slack,
// clamped >= 0 for clamped queries). Stop when ALL QC queries have >= NEEDQ
// kept candidates within their bound (tail-duplicated queries mirror q0 and
// never delay the stop). dmin[q] = min value ever not-kept (exact truncation
// test). cnt/bnd2 from the final stop test.
template <int K, int NEEDQ>
__device__ __forceinline__ void wave_grid_knn_q(
    int g, int cx, int cy, int cz,
    const float (&qx)[QC], const float (&qy)[QC], const float (&qz)[QC],
    const float4* __restrict__ sorted, const unsigned* __restrict__ pack,
    unsigned* sS, unsigned* sC, unsigned* sPre, int lane,
    float (&a)[QC][K], float (&dminq)[QC], int (&cntq)[QC],
    float (&bnd2q)[QC]) {
  float fq[QC];
#pragma unroll
  for (int q = 0; q < QC; ++q) {
    float fx = fminf(qx[q] - (RLO + cx * H), (RLO + (cx + 1) * H) - qx[q]);
    float fy = fminf(qy[q] - (RLO + cy * H), (RLO + (cy + 1) * H) - qy[q]);
    float fz = fminf(qz[q] - (RLO + cz * H), (RLO + (cz + 1) * H) - qz[q]);
    fq[q] = fminf(fx, fminf(fy, fz));      // may be <0 for clamped queries
  }
  const int base = g * NCELLS;
  for (int m = 0; m <= GRID; ++m) {
    const int zlo = max(cz - m, 0), zhi = min(cz + m, GRID - 1);
    const int ylo = max(cy - m, 0), yhi = min(cy + m, GRID - 1);
    const int xlo = max(cx - m, 0), xhi = min(cx + m, GRID - 1);
    const int ny = yhi - ylo + 1;
    const int nrows = (zhi - zlo + 1) * ny;
    for (int rb = 0; rb < nrows; rb += 64) {
      const int rho = rb + lane;
      const bool act = rho < nrows;
      const int rr = act ? rho : 0;
      const int z = zlo + rr / ny, y = ylo + rr % ny;
      const int dza = abs(z - cz), dya = abs(y - cy);
      const bool bdry = (dza == m) || (dya == m);
      unsigned stA = 0, cnA = 0, stB = 0, cnB = 0;
      const int rowbase = base + (z * GRID + y) * GRID;
      if (act) {
        if (bdry) {  // full (clamped) x-range: contiguous segment, 2 loads
          unsigned plo = pack[rowbase + xlo];
          unsigned phi = pack[rowbase + xhi];
          stA = plo >> 14;
          cnA = ((phi >> 14) + (phi & 16383u)) - stA;
        } else {     // interior row: only the two new x = cx +- m cells
          int xl = cx - m, xr = cx + m;
          if (xl >= 0) { unsigned p = pack[rowbase + xl]; stA = p >> 14; cnA = p & 16383u; }
          if (xr < GRID) { unsigned p = pack[rowbase + xr]; stB = p >> 14; cnB = p & 16383u; }
        }
      }
      // ballot-compact nonempty segments into wave-private LDS
      unsigned long long mA = __ballot(cnA > 0);
      unsigned long long mB = __ballot(cnB > 0);
      int nA = __popcll(mA);
      int nseg = nA + __popcll(mB);
      if (nseg == 0) continue;
      int slA = lanerank(mA), slB = nA + lanerank(mB);
      if (cnA > 0) { sS[slA] = stA; sC[slA] = cnA; }
      if (cnB > 0) { sS[slB] = stB; sC[slB] = cnB; }
      // exclusive prefix over segment counts (<=128 segs, 2 halves of 64)
      unsigned total = 0;
      for (int h = 0; h < 2; ++h) {
        int sl = h * 64 + lane;
        unsigned v = (sl < nseg) ? sC[sl] : 0u;
        unsigned inc = v;
#pragma unroll
        for (int s2 = 1; s2 < 64; s2 <<= 1) {
          unsigned t = __shfl_up(inc, s2, 64);
          if (lane >= s2) inc += t;
        }
        if (sl < nseg) sPre[sl] = total + inc - v;
        total += __shfl(inc, 63, 64);
        if (nseg <= 64) break;
      }
      // candidates 64-wide across segment boundaries; depth-adaptive search
      int sh0 = (nseg > 1) ? (1 << (31 - __clz(nseg - 1))) : 0;
      for (unsigned cb = 0; cb < total; cb += 64) {
        unsigned c = cb + (unsigned)lane;
        bool cact = c < total;
        unsigned cc = cact ? c : (total - 1);
        int lo = 0;  // max seg with sPre[seg] <= cc (sPre[0]==0)
        for (int sh = sh0; sh; sh >>= 1) {
          int mid = lo + sh;
          if (mid < nseg && sPre[mid] <= cc) lo = mid;
        }
        float4 p = sorted[sS[lo] + (cc - sPre[lo])];
#pragma unroll
        for (int q = 0; q < QC; ++q) {
          float d = cact ? sqd3(qx[q], qy[q], qz[q], p) : INFINITY;
          dminq[q] = fminf(dminq[q], fmaxf(d, a[q][K - 1]));
          insertK(a[q], d);
        }
      }
    }
    // stop test: all queries have >= NEEDQ kept candidates within bound
#pragma unroll
    for (int q = 0; q < QC; ++q) {
      float bnd = fmaxf((float)m * H + fq[q], 0.0f) * 0.999f;
      bnd2q[q] = bnd * bnd;
    }
    int cpA = 0, cpB = 0;          // pack counts: q0 | q1<<16, q2
#pragma unroll
    for (int k = 0; k < K; ++k) {
      cpA += (a[0][k] <= bnd2q[0] ? 1 : 0) + (a[1][k] <= bnd2q[1] ? 65536 : 0);
      cpB += (a[2][k] <= bnd2q[2] ? 1 : 0);
    }
#pragma unroll
    for (int s2 = 1; s2 < 64; s2 <<= 1) {
      cpA += __shfl_xor(cpA, s2, 64);
      cpB += __shfl_xor(cpB, s2, 64);
    }
    cntq[0] = cpA & 0xffff;
    cntq[1] = cpA >> 16;
    cntq[2] = cpB;
    bool okall = (cntq[0] >= NEEDQ) && (cntq[1] >= NEEDQ) && (cntq[2] >= NEEDQ);
    bool covered = (zlo == 0 && zhi == GRID - 1 && ylo == 0 && yhi == GRID - 1 &&
                    xlo == 0 && xhi == GRID - 1);
    if (okall || covered) break;
  }
}

// Per-query epilogue: compact candidates <= tau, wave-sort, return ascending
// sorted value (lanes 0..15 = top-16 squared dists). bad = exactness lost.
template <int K>
__device__ __forceinline__ float epilogue16(float (&aq)[K], float dmin,
                                            int cnt, float bnd2, float* cbuf,
                                            int lane, bool& bad) {
  float tau;
  if (cnt >= KNN && cnt <= 64) {
    tau = bnd2;
  } else {
    float slm = bitonic_sort64(aq[0], lane);   // lane minima never truncated
    tau = __shfl(slm, 15, 64);
  }
  int tot = 0;
  int idxk[K];
#pragma unroll
  for (int k = 0; k < K; ++k) {
    unsigned long long mk = __ballot(aq[k] <= tau);
    idxk[k] = tot + lanerank(mk);
    tot += __popcll(mk);
  }
#pragma unroll
  for (int k = 0; k < K; ++k)
    if (aq[k] <= tau && idxk[k] < 64) cbuf[idxk[k]] = aq[k];
  float v = (lane < tot) ? cbuf[lane] : INFINITY;  // same-wave: no barrier
  v = bitonic_sort64(v, lane);
  float f15 = __shfl(v, 15, 64);
  // EXACT validity: a lost top-16 member implies dmin <= v16_true <= f15.
  bad = (tot > 64) || (__ballot(dmin <= f15) != 0ull);
  return v;
}

// ---------- build ----------
__global__ __launch_bounds__(256) void count_kernel(
    const float* __restrict__ yp, const float* __restrict__ yt,
    unsigned* __restrict__ counts, int* __restrict__ pflat,
    unsigned* __restrict__ prank, unsigned* __restrict__ wcnt) {
  if (blockIdx.x == 0 && threadIdx.x < 16) wcnt[threadIdx.x] = 0;  // pre-pack
  int t = blockIdx.x * 256 + threadIdx.x;          // 0 .. 2*NROWS-1
  const float* src;
  int g;
  if (t < NROWS) { src = yp + 3 * t; g = 2 * (t >> 13); }
  else { int u = t - NROWS; src = yt + 3 * u; g = 2 * (u >> 13) + 1; }
  int flat = g * NCELLS + (cellof(src[2]) * GRID + cellof(src[1])) * GRID + cellof(src[0]);
  unsigned r = atomicAdd(&counts[flat], 1u);
  pflat[t] = flat;
  prank[t] = r;
}

__global__ __launch_bounds__(1024) void scan1_kernel(
    const unsigned* __restrict__ counts, unsigned* __restrict__ partial,
    unsigned* __restrict__ aux) {
  __shared__ unsigned ws[16];
  const int t = threadIdx.x, lane = t & 63, wave = t >> 6;
  const int tid = blockIdx.x * 1024 + t;
  unsigned v = counts[tid];
  unsigned inc = v;
#pragma unroll
  for (int off = 1; off < 64; off <<= 1) {
    unsigned u = __shfl_up(inc, off, 64);
    if (lane >= off) inc += u;
  }
  if (lane == 63) ws[wave] = inc;
  __syncthreads();
  unsigned wex = 0;
  if (wave == 0) {
    unsigned o = (lane < 16) ? ws[lane] : 0u;
    unsigned wi = o;
#pragma unroll
    for (int off = 1; off < 16; off <<= 1) {
      unsigned u = __shfl_up(wi, off, 64);
      if (lane >= off) wi += u;
    }
    if (lane < 16) ws[lane] = wi - o;
  }
  __syncthreads();
  wex = ws[wave];
  partial[tid] = wex + inc - v;
  if (t == 1023) aux[blockIdx.x] = wex + inc;
}

// Fused scan2+pack + flat worklist build.
// cellinfo pack: global start (<=16b used of 18) << 14 | count (14b)
// worklist entry: b<<30 | task<<28 | cell<<13 | chunk_j
//   task 0: FUSED T-cell item (T queries vs P grid AND T grid)
//   task 2: P-cell item (P queries vs T grid -> mincol)
__global__ __launch_bounds__(1024) void pack_kernel(
    const unsigned* __restrict__ counts, const unsigned* __restrict__ partial,
    const unsigned* __restrict__ aux, unsigned* __restrict__ pack,
    unsigned* __restrict__ wcnt, unsigned* __restrict__ wlist) {
  __shared__ unsigned sa[2];
  const int t = threadIdx.x;
  if (t < 128) {
    unsigned v = (t < (int)blockIdx.x) ? aux[t] : 0u;
#pragma unroll
    for (int s = 1; s < 64; s <<= 1) v += __shfl_xor(v, s, 64);
    if ((t & 63) == 0) sa[t >> 6] = v;
  }
  __syncthreads();
  unsigned base = sa[0] + sa[1];
  int i = blockIdx.x * 1024 + t;
  unsigned cnti = counts[i];
  pack[i] = ((partial[i] + base) << 14) | cnti;
  if (cnti > 0) {
    int g = i >> 15;                 // NCELLS = 2^15
    unsigned b = (unsigned)(g >> 1);
    unsigned cellw = (unsigned)(i & (NCELLS - 1));
    unsigned nch = (cnti + QC - 1) / QC;
    unsigned task = (g & 1) ? 0u : 2u;
    unsigned slot = atomicAdd(&wcnt[4], nch);
    for (unsigned j = 0; j < nch; ++j)
      wlist[slot + j] = (b << 30) | (task << 28) | (cellw << 13) | j;
  }
}

__global__ __launch_bounds__(256) void scatter_kernel(
    const float* __restrict__ yp, const float* __restrict__ yt,
    const unsigned* __restrict__ pack, const int* __restrict__ pflat,
    const unsigned* __restrict__ prank, float4* __restrict__ sorted) {
  int t = blockIdx.x * 256 + threadIdx.x;
  const float* src;
  int row;
  if (t < NROWS) { row = t; src = yp + 3 * t; }
  else { row = t - NROWS; src = yt + 3 * row; }
  unsigned pos = (pack[pflat[t]] >> 14) + prank[t];
  sorted[pos] = make_float4(src[0], src[1], src[2], __int_as_float(row));
}

// ---------- queries: claim-scheduled waves over (cell,chunk) items ----------
// Fused T items: same wave runs kNN vs P grid then vs T grid for QC queries,
// emitting per-row scalars minrow (=knnP[0]) and dens (=sum_k|knnP_k-knnT_k|)
// plus one exactness flag. P items: mincol (exact via per-query stop rule).
__global__ __launch_bounds__(256) void query_kernel(
    const float4* __restrict__ sorted, const unsigned* __restrict__ pack,
    unsigned* __restrict__ wcnt, const unsigned* __restrict__ wlist,
    float* __restrict__ minrow_arr, float* __restrict__ densrow,
    float* __restrict__ mincol_arr, unsigned* __restrict__ flags) {
  __shared__ unsigned sb[4][3][SEGCAP];
  __shared__ float cbw[4][64];
  __shared__ float vPw[4][QC][16];       // sqrt'd P-side top-16 stash
  const int wave = threadIdx.x >> 6, lane = threadIdx.x & 63;
  unsigned* sS = sb[wave][0];
  unsigned* sC = sb[wave][1];
  unsigned* sP = sb[wave][2];
  float* cbuf = cbw[wave];
  const unsigned nwork = wcnt[4];
  for (;;) {
    unsigned wrk;
    if (lane == 0) wrk = atomicAdd(&wcnt[5], 1u);   // dynamic balance
    wrk = (unsigned)__shfl((int)wrk, 0, 64);
    if (wrk >= nwork) break;
    const unsigned e = wlist[wrk];
    const int b = (int)((e >> 30) & 1u);
    const int task = (int)((e >> 28) & 3u);
    const int cell = (int)((e >> 13) & 32767u);
    const int qoff = (int)(e & 8191u) * QC;
    const int qg = (task == 2) ? 2 * b : 2 * b + 1;
    const unsigned pc = pack[qg * NCELLS + cell];
    const int cstart = (int)(pc >> 14);
    const int ccnt = (int)(pc & 16383u);
    const int nq = min(QC, ccnt - qoff);
    const int cx = cell & (GRID - 1), cy = (cell >> 5) & (GRID - 1), cz = cell >> 10;

    float qx[QC], qy[QC], qz[QC];
    int rowq[QC];
#pragma unroll
    for (int q = 0; q < QC; ++q) {   // duplicate last query into empty slots
      float4 eq = sorted[cstart + qoff + min(q, nq - 1)];
      qx[q] = eq.x; qy[q] = eq.y; qz[q] = eq.z;
      rowq[q] = __float_as_int(eq.w);
    }

    if (task == 0) {
      // ---- pass 1: T queries vs P grid ----
      float a[QC][KC];
      float dminq[QC];
      int cntq[QC];
      float bnd2q[QC];
      unsigned badbits = 0;
#pragma unroll
      for (int q = 0; q < QC; ++q) {
        dminq[q] = INFINITY;
#pragma unroll
        for (int k = 0; k < KC; ++k) a[q][k] = INFINITY;
      }
      wave_grid_knn_q<KC, KNN>(2 * b, cx, cy, cz, qx, qy, qz, sorted, pack,
                               sS, sC, sP, lane, a, dminq, cntq, bnd2q);
#pragma unroll
      for (int q = 0; q < QC; ++q) {
        if (q >= nq) break;                          // wave-uniform
        bool bad;
        float v = epilogue16(a[q], dminq[q], cntq[q], bnd2q[q], cbuf, lane, bad);
        if (lane < KNN) vPw[wave][q][lane] = sqrtf(v);
        if (bad) badbits |= (1u << q);
      }
      // ---- pass 2: T queries vs T grid ----
#pragma unroll
      for (int q = 0; q < QC; ++q) {
        dminq[q] = INFINITY;
#pragma unroll
        for (int k = 0; k < KC; ++k) a[q][k] = INFINITY;
      }
      wave_grid_knn_q<KC, KNN>(2 * b + 1, cx, cy, cz, qx, qy, qz, sorted, pack,
                               sS, sC, sP, lane, a, dminq, cntq, bnd2q);
#pragma unroll
      for (int q = 0; q < QC; ++q) {
        if (q >= nq) break;
        bool bad;
        float v = epilogue16(a[q], dminq[q], cntq[q], bnd2q[q], cbuf, lane, bad);
        float vp = (lane < KNN) ? vPw[wave][q][lane] : 0.0f;
        float d = (lane < KNN) ? fabsf(vp - sqrtf(v)) : 0.0f;
#pragma unroll
        for (int s2 = 1; s2 < 16; s2 <<= 1) d += __shfl_xor(d, s2, 64);
        float mr = __shfl(vp, 0, 64);                // knnP[0] from lane 0
        if (lane == 0) {
          minrow_arr[rowq[q]] = mr;
          densrow[rowq[q]] = d;
          flags[rowq[q]] = ((badbits >> q) & 1u) | bad ? 1u : 0u;
        }
      }
    } else {
      // ---- P queries vs T grid -> mincol (exact: lane minima never lost) ----
      float a1[QC][1];
      float dminq[QC];
      int cntq[QC];
      float bnd2q[QC];
#pragma unroll
      for (int q = 0; q < QC; ++q) { a1[q][0] = INFINITY; dminq[q] = INFINITY; }
      wave_grid_knn_q<1, 1>(2 * b + 1, cx, cy, cz, qx, qy, qz, sorted, pack,
                            sS, sC, sP, lane, a1, dminq, cntq, bnd2q);
#pragma unroll
      for (int q = 0; q < QC; ++q) {
        if (q >= nq) break;
        float v = a1[q][0];
#pragma unroll
        for (int s2 = 1; s2 < 64; s2 <<= 1) v = fminf(v, __shfl_xor(v, s2, 64));
        if (lane == 0) mincol_arr[rowq[q]] = sqrtf(v);
      }
    }
  }
}

// Guaranteed-exact dense fallback over one grid slice (8192 points):
// lane r (r<16) returns the r-th smallest squared distance.
__device__ float exact16_rowlist(const float4* __restrict__ base,
                                 float qx, float qy, float qz, int lane) {
  float a[KNN];
#pragma unroll
  for (int k = 0; k < KNN; ++k) a[k] = INFINITY;
  for (int s = 0; s < NPTS / 64; ++s) {
    float d = sqd3(qx, qy, qz, base[s * 64 + lane]);
    insertK(a, d);
  }
  float res = INFINITY;
#pragma unroll 1
  for (int r = 0; r < KNN; ++r) {
    float v = a[0];
    int idx = lane;
#pragma unroll
    for (int s = 1; s < 64; s <<= 1) {
      float ov = __shfl_xor(v, s, 64);
      int oi = __shfl_xor(idx, s, 64);
      bool take = (ov < v) || (ov == v && oi < idx);
      v = take ? ov : v;
      idx = take ? oi : idx;
    }
    if (lane == r) res = v;
    if (lane == idx) {
#pragma unroll
      for (int k = 0; k < KNN - 1; ++k) a[k] = a[k + 1];
      a[KNN - 1] = INFINITY;
    }
  }
  return res;
}

// Fused tail+combine: each wave densely repairs flagged rows among its 64
// rows (expected ~0), then deterministic double partials over per-row
// scalars (block-ordered; bit-stable across runs).
__global__ __launch_bounds__(256) void combine_kernel(
    const float* __restrict__ yt, const float4* __restrict__ sorted,
    const unsigned* __restrict__ flags, float* __restrict__ minrow_arr,
    float* __restrict__ densrow, const float* __restrict__ mincol_arr,
    double* __restrict__ pd) {
  __shared__ double s1[256], s2[256], s3[256];
  const int t = threadIdx.x, lane = t & 63, wave = t >> 6;
  const int row0 = blockIdx.x * 256;
  const int rbase = row0 + wave * 64;
  unsigned f0 = flags[rbase + lane];
  unsigned long long m0 = __ballot(f0 != 0u);
  while (m0) {                                        // wave-uniform loop
    int rr = __ffsll(m0) - 1; m0 &= m0 - 1;
    int row = rbase + rr;
    int bb = row >> 13;
    const float* q = yt + 3 * row;
    float sPq = exact16_rowlist(sorted + (size_t)(2 * bb) * NPTS,
                                q[0], q[1], q[2], lane);
    float sTq = exact16_rowlist(sorted + (size_t)(2 * bb + 1) * NPTS,
                                q[0], q[1], q[2], lane);
    float vp = (lane < KNN) ? sqrtf(sPq) : 0.0f;
    float vt = (lane < KNN) ? sqrtf(sTq) : 0.0f;
    float d = fabsf(vp - vt);
#pragma unroll
    for (int s = 1; s < 16; s <<= 1) d += __shfl_xor(d, s, 64);
    float mr = __shfl(vp, 0, 64);
    if (lane == 0) { minrow_arr[row] = mr; densrow[row] = d; }
  }
  __syncthreads();  // repairs (global writes by this block) visible block-wide
  const int row = row0 + t;
  s1[t] = (double)minrow_arr[row];
  s2[t] = (double)mincol_arr[row];
  s3[t] = (double)densrow[row];
  __syncthreads();
  for (int off = 128; off > 0; off >>= 1) {
    if (t < off) { s1[t] += s1[t + off]; s2[t] += s2[t + off]; s3[t] += s3[t + off]; }
    __syncthreads();
  }
  if (t == 0) {
    pd[blockIdx.x * 3 + 0] = s1[0];
    pd[blockIdx.x * 3 + 1] = s2[0];
    pd[blockIdx.x * 3 + 2] = s3[0];
  }
}

__global__ __launch_bounds__(64) void finalize_kernel(
    const double* __restrict__ pd, float* __restrict__ out) {
  const int t = threadIdx.x;
  double a = pd[t * 3], b = pd[t * 3 + 1], c = pd[t * 3 + 2];
#pragma unroll
  for (int s = 32; s >= 1; s >>= 1) {
    a += __shfl_down(a, s, 64);
    b += __shfl_down(b, s, 64);
    c += __shfl_down(c, s, 64);
  }
  if (t == 0) {
    double shape = 0.5 * (a + b) / (double)NROWS;
    double dens = c / ((double)NROWS * KNN);
    out[0] = (float)(shape + dens);
    out[1] = (float)shape;
    out[2] = (float)dens;
  }
}

extern "C" void kernel_launch(void* const* d_in, const int* in_sizes, int n_in,
                              void* d_out, int out_size, void* d_ws, size_t ws_size,
                              hipStream_t stream) {
  (void)in_sizes; (void)n_in; (void)out_size; (void)ws_size;
  const float* yp = (const float*)d_in[0];  // y_pred [B, N, 3]
  const float* yt = (const float*)d_in[1];  // y_true [B, N, 3]
  char* w = (char*)d_ws;
  unsigned* counts  = (unsigned*)w;  w += TOTCELLS * 4;       // 512 KB
  unsigned* partial = (unsigned*)w;  w += TOTCELLS * 4;       // 512 KB
  unsigned* aux     = (unsigned*)w;  w += 512;
  unsigned* pack    = (unsigned*)w;  w += TOTCELLS * 4;       // 512 KB
  int*      pflat   = (int*)w;       w += 2 * NROWS * 4;      // 128 KB
  unsigned* prank   = (unsigned*)w;  w += 2 * NROWS * 4;      // 128 KB
  float4*   sorted  = (float4*)w;    w += 2 * NROWS * 16;     // 1 MB
  float*    minrow  = (float*)w;     w += NROWS * 4;          // 64 KB
  float*    densrow = (float*)w;     w += NROWS * 4;          // 64 KB
  float*    mincol  = (float*)w;     w += NROWS * 4;          // 64 KB
  unsigned* flags   = (unsigned*)w;  w += NROWS * 4;          // written every launch
  double*   pd      = (double*)w;    w += 64 * 3 * 8;
  unsigned* wcnt    = (unsigned*)w;  w += 64;                 // [4]=items [5]=claim
  unsigned* wlist   = (unsigned*)w;  w += WLCAP * 4;          // 192 KB
  float* out = (float*)d_out;

  hipMemsetAsync(counts, 0, (size_t)TOTCELLS * 4, stream);
  count_kernel<<<2 * NROWS / 256, 256, 0, stream>>>(yp, yt, counts, pflat, prank, wcnt);
  scan1_kernel<<<SCAN_BLOCKS, 1024, 0, stream>>>(counts, partial, aux);
  pack_kernel<<<SCAN_BLOCKS, 1024, 0, stream>>>(counts, partial, aux, pack, wcnt, wlist);
  scatter_kernel<<<2 * NROWS / 256, 256, 0, stream>>>(yp, yt, pack, pflat, prank, sorted);
  query_kernel<<<QBLOCKS, 256, 0, stream>>>(sorted, pack, wcnt, wlist,
                                            minrow, densrow, mincol, flags);
  combine_kernel<<<64, 256, 0, stream>>>(yt, sorted, flags, minrow, densrow,
                                         mincol, pd);
  finalize_kernel<<<1, 64, 0, stream>>>(pd, out);
}

// Round 9
// 162.601 us; speedup vs baseline: 2.1620x; 2.1620x over previous
//
#include <hip/hip_runtime.h>
#include <math.h>

#define NPTS 8192
#define NB 2
#define NROWS (NB * NPTS)
#define KNN 16
#define KC 6          // per-lane kept candidates (truncated sorted list)

// Spatial grid: 32^3 cells of width H. 4 grids: P/T x batch. g: P=2b, T=2b+1.
#define GRID 32
#define NCELLS (GRID * GRID * GRID)        // 32768
#define TOTCELLS (4 * NCELLS)              // 131072
#define H 0.35f
#define RLO (-5.6f)
#define INVH (1.0f / H)
#define SCAN_BLOCKS 128
#define SEGCAP 132                          // >= 2*64 segments per row-chunk

// QC co-celled queries share one wave's enumeration stream. T-cell items are
// FUSED (P-grid + T-grid kNN in one item, scalar outputs). Scheduling:
// PARTITIONED dynamic claims -- 32 counters on separate cachelines, item i
// in partition i&31, wave wid draws from partition wid&31 only. [R6 lesson:
// a SINGLE claim counter serializes ~15ns/atomic -> 300us floor at 20k
// claims; R5 lesson: static stride loses ~40us to stragglers.]
#define QC 3
#define WLCAP 49152
#define QBLOCKS 2048
#define NPART 32
#define CTRSTRIDE 16      // u32s between counters = 64 B

__device__ __forceinline__ int cellof(float x) {
  int c = (int)floorf((x - RLO) * INVH);
  return min(max(c, 0), GRID - 1);
}

__device__ __forceinline__ float sqd3(float qx, float qy, float qz, float4 c) {
  float dx = qx - c.x, dy = qy - c.y, dz = qz - c.z;
  return fmaf(dx, dx, fmaf(dy, dy, dz * dz));
}

__device__ __forceinline__ int lanerank(unsigned long long mk) {
  return __builtin_amdgcn_mbcnt_hi((unsigned)(mk >> 32),
                                   __builtin_amdgcn_mbcnt_lo((unsigned)mk, 0));
}

// Guarded insert into ascending sorted-K list (per-lane).
template <int K>
__device__ __forceinline__ void insertK(float (&a)[K], float d) {
  if (d < a[K - 1]) {
    a[K - 1] = d;
#pragma unroll
    for (int k = K - 1; k > 0; --k) {
      float lo = fminf(a[k - 1], a[k]);
      a[k] = fmaxf(a[k - 1], a[k]);
      a[k - 1] = lo;
    }
  }
}

// Full ascending bitonic sort of one value per lane across the 64-lane wave.
__device__ __forceinline__ float bitonic_sort64(float v, int lane) {
#pragma unroll
  for (int k = 2; k <= 64; k <<= 1) {
#pragma unroll
    for (int j = k >> 1; j >= 1; j >>= 1) {
      float o = __shfl_xor(v, j, 64);
      bool up = ((lane & k) == 0);
      bool lower = ((lane & j) == 0);
      float mn = fminf(v, o), mx = fmaxf(v, o);
      v = (up == lower) ? mn : mx;
    }
  }
  return v;
}

// Wave-cooperative kNN for QC co-celled queries (R0 enumeration structure:
// streaming candidates from global, expanding Chebyshev shells on the
// counting-sorted grid). Exactness per query q: after completing shell m, an
// unvisited point is > (m*H + fq[q]) away (fq = min per-axis in-cell slack,
// clamped >= 0 for clamped queries). Stop when ALL QC queries have >= NEEDQ
// kept candidates within their bound (tail-duplicated queries mirror q0 and
// never delay the stop). dmin[q] = min value ever not-kept (exact truncation
// test). cnt/bnd2 from the final stop test.
template <int K, int NEEDQ>
__device__ __forceinline__ void wave_grid_knn_q(
    int g, int cx, int cy, int cz,
    const float (&qx)[QC], const float (&qy)[QC], const float (&qz)[QC],
    const float4* __restrict__ sorted, const unsigned* __restrict__ pack,
    unsigned* sS, unsigned* sC, unsigned* sPre, int lane,
    float (&a)[QC][K], float (&dminq)[QC], int (&cntq)[QC],
    float (&bnd2q)[QC]) {
  float fq[QC];
#pragma unroll
  for (int q = 0; q < QC; ++q) {
    float fx = fminf(qx[q] - (RLO + cx * H), (RLO + (cx + 1) * H) - qx[q]);
    float fy = fminf(qy[q] - (RLO + cy * H), (RLO + (cy + 1) * H) - qy[q]);
    float fz = fminf(qz[q] - (RLO + cz * H), (RLO + (cz + 1) * H) - qz[q]);
    fq[q] = fminf(fx, fminf(fy, fz));      // may be <0 for clamped queries
  }
  const int base = g * NCELLS;
  for (int m = 0; m <= GRID; ++m) {
    const int zlo = max(cz - m, 0), zhi = min(cz + m, GRID - 1);
    const int ylo = max(cy - m, 0), yhi = min(cy + m, GRID - 1);
    const int xlo = max(cx - m, 0), xhi = min(cx + m, GRID - 1);
    const int ny = yhi - ylo + 1;
    const int nrows = (zhi - zlo + 1) * ny;
    for (int rb = 0; rb < nrows; rb += 64) {
      const int rho = rb + lane;
      const bool act = rho < nrows;
      const int rr = act ? rho : 0;
      const int z = zlo + rr / ny, y = ylo + rr % ny;
      const int dza = abs(z - cz), dya = abs(y - cy);
      const bool bdry = (dza == m) || (dya == m);
      unsigned stA = 0, cnA = 0, stB = 0, cnB = 0;
      const int rowbase = base + (z * GRID + y) * GRID;
      if (act) {
        if (bdry) {  // full (clamped) x-range: contiguous segment, 2 loads
          unsigned plo = pack[rowbase + xlo];
          unsigned phi = pack[rowbase + xhi];
          stA = plo >> 14;
          cnA = ((phi >> 14) + (phi & 16383u)) - stA;
        } else {     // interior row: only the two new x = cx +- m cells
          int xl = cx - m, xr = cx + m;
          if (xl >= 0) { unsigned p = pack[rowbase + xl]; stA = p >> 14; cnA = p & 16383u; }
          if (xr < GRID) { unsigned p = pack[rowbase + xr]; stB = p >> 14; cnB = p & 16383u; }
        }
      }
      // ballot-compact nonempty segments into wave-private LDS
      unsigned long long mA = __ballot(cnA > 0);
      unsigned long long mB = __ballot(cnB > 0);
      int nA = __popcll(mA);
      int nseg = nA + __popcll(mB);
      if (nseg == 0) continue;
      int slA = lanerank(mA), slB = nA + lanerank(mB);
      if (cnA > 0) { sS[slA] = stA; sC[slA] = cnA; }
      if (cnB > 0) { sS[slB] = stB; sC[slB] = cnB; }
      // exclusive prefix over segment counts (<=128 segs, 2 halves of 64)
      unsigned total = 0;
      for (int h = 0; h < 2; ++h) {
        int sl = h * 64 + lane;
        unsigned v = (sl < nseg) ? sC[sl] : 0u;
        unsigned inc = v;
#pragma unroll
        for (int s2 = 1; s2 < 64; s2 <<= 1) {
          unsigned t = __shfl_up(inc, s2, 64);
          if (lane >= s2) inc += t;
        }
        if (sl < nseg) sPre[sl] = total + inc - v;
        total += __shfl(inc, 63, 64);
        if (nseg <= 64) break;
      }
      // candidates 64-wide across segment boundaries; depth-adaptive search
      int sh0 = (nseg > 1) ? (1 << (31 - __clz(nseg - 1))) : 0;
      for (unsigned cb = 0; cb < total; cb += 64) {
        unsigned c = cb + (unsigned)lane;
        bool cact = c < total;
        unsigned cc = cact ? c : (total - 1);
        int lo = 0;  // max seg with sPre[seg] <= cc (sPre[0]==0)
        for (int sh = sh0; sh; sh >>= 1) {
          int mid = lo + sh;
          if (mid < nseg && sPre[mid] <= cc) lo = mid;
        }
        float4 p = sorted[sS[lo] + (cc - sPre[lo])];
#pragma unroll
        for (int q = 0; q < QC; ++q) {
          float d = cact ? sqd3(qx[q], qy[q], qz[q], p) : INFINITY;
          dminq[q] = fminf(dminq[q], fmaxf(d, a[q][K - 1]));
          insertK(a[q], d);
        }
      }
    }
    // stop test: all queries have >= NEEDQ kept candidates within bound
#pragma unroll
    for (int q = 0; q < QC; ++q) {
      float bnd = fmaxf((float)m * H + fq[q], 0.0f) * 0.999f;
      bnd2q[q] = bnd * bnd;
    }
    int cpA = 0, cpB = 0;          // pack counts: q0 | q1<<16, q2
#pragma unroll
    for (int k = 0; k < K; ++k) {
      cpA += (a[0][k] <= bnd2q[0] ? 1 : 0) + (a[1][k] <= bnd2q[1] ? 65536 : 0);
      cpB += (a[2][k] <= bnd2q[2] ? 1 : 0);
    }
#pragma unroll
    for (int s2 = 1; s2 < 64; s2 <<= 1) {
      cpA += __shfl_xor(cpA, s2, 64);
      cpB += __shfl_xor(cpB, s2, 64);
    }
    cntq[0] = cpA & 0xffff;
    cntq[1] = cpA >> 16;
    cntq[2] = cpB;
    bool okall = (cntq[0] >= NEEDQ) && (cntq[1] >= NEEDQ) && (cntq[2] >= NEEDQ);
    bool covered = (zlo == 0 && zhi == GRID - 1 && ylo == 0 && yhi == GRID - 1 &&
                    xlo == 0 && xhi == GRID - 1);
    if (okall || covered) break;
  }
}

// Per-query epilogue: compact candidates <= tau, wave-sort, return ascending
// sorted value (lanes 0..15 = top-16 squared dists). bad = exactness lost.
template <int K>
__device__ __forceinline__ float epilogue16(float (&aq)[K], float dmin,
                                            int cnt, float bnd2, float* cbuf,
                                            int lane, bool& bad) {
  float tau;
  if (cnt >= KNN && cnt <= 64) {
    tau = bnd2;
  } else {
    float slm = bitonic_sort64(aq[0], lane);   // lane minima never truncated
    tau = __shfl(slm, 15, 64);
  }
  int tot = 0;
  int idxk[K];
#pragma unroll
  for (int k = 0; k < K; ++k) {
    unsigned long long mk = __ballot(aq[k] <= tau);
    idxk[k] = tot + lanerank(mk);
    tot += __popcll(mk);
  }
#pragma unroll
  for (int k = 0; k < K; ++k)
    if (aq[k] <= tau && idxk[k] < 64) cbuf[idxk[k]] = aq[k];
  float v = (lane < tot) ? cbuf[lane] : INFINITY;  // same-wave: no barrier
  v = bitonic_sort64(v, lane);
  float f15 = __shfl(v, 15, 64);
  // EXACT validity: a lost top-16 member implies dmin <= v16_true <= f15.
  bad = (tot > 64) || (__ballot(dmin <= f15) != 0ull);
  return v;
}

// ---------- build ----------
__global__ __launch_bounds__(256) void count_kernel(
    const float* __restrict__ yp, const float* __restrict__ yt,
    unsigned* __restrict__ counts, int* __restrict__ pflat,
    unsigned* __restrict__ prank, unsigned* __restrict__ wcnt) {
  if (blockIdx.x == 0) {                 // zero item count + claim counters
#pragma unroll
    for (int j = 0; j < 4; ++j) wcnt[threadIdx.x * 4 + j] = 0;  // 1024 u32
  }
  int t = blockIdx.x * 256 + threadIdx.x;          // 0 .. 2*NROWS-1
  const float* src;
  int g;
  if (t < NROWS) { src = yp + 3 * t; g = 2 * (t >> 13); }
  else { int u = t - NROWS; src = yt + 3 * u; g = 2 * (u >> 13) + 1; }
  int flat = g * NCELLS + (cellof(src[2]) * GRID + cellof(src[1])) * GRID + cellof(src[0]);
  unsigned r = atomicAdd(&counts[flat], 1u);
  pflat[t] = flat;
  prank[t] = r;
}

__global__ __launch_bounds__(1024) void scan1_kernel(
    const unsigned* __restrict__ counts, unsigned* __restrict__ partial,
    unsigned* __restrict__ aux) {
  __shared__ unsigned ws[16];
  const int t = threadIdx.x, lane = t & 63, wave = t >> 6;
  const int tid = blockIdx.x * 1024 + t;
  unsigned v = counts[tid];
  unsigned inc = v;
#pragma unroll
  for (int off = 1; off < 64; off <<= 1) {
    unsigned u = __shfl_up(inc, off, 64);
    if (lane >= off) inc += u;
  }
  if (lane == 63) ws[wave] = inc;
  __syncthreads();
  unsigned wex = 0;
  if (wave == 0) {
    unsigned o = (lane < 16) ? ws[lane] : 0u;
    unsigned wi = o;
#pragma unroll
    for (int off = 1; off < 16; off <<= 1) {
      unsigned u = __shfl_up(wi, off, 64);
      if (lane >= off) wi += u;
    }
    if (lane < 16) ws[lane] = wi - o;
  }
  __syncthreads();
  wex = ws[wave];
  partial[tid] = wex + inc - v;
  if (t == 1023) aux[blockIdx.x] = wex + inc;
}

// Fused scan2+pack + flat worklist build.
// cellinfo pack: global start (<=16b used of 18) << 14 | count (14b)
// worklist entry: b<<30 | task<<28 | cell<<13 | chunk_j
//   task 0: FUSED T-cell item (T queries vs P grid AND T grid)
//   task 2: P-cell item (P queries vs T grid -> mincol)
__global__ __launch_bounds__(1024) void pack_kernel(
    const unsigned* __restrict__ counts, const unsigned* __restrict__ partial,
    const unsigned* __restrict__ aux, unsigned* __restrict__ pack,
    unsigned* __restrict__ wcnt, unsigned* __restrict__ wlist) {
  __shared__ unsigned sa[2];
  const int t = threadIdx.x;
  if (t < 128) {
    unsigned v = (t < (int)blockIdx.x) ? aux[t] : 0u;
#pragma unroll
    for (int s = 1; s < 64; s <<= 1) v += __shfl_xor(v, s, 64);
    if ((t & 63) == 0) sa[t >> 6] = v;
  }
  __syncthreads();
  unsigned base = sa[0] + sa[1];
  int i = blockIdx.x * 1024 + t;
  unsigned cnti = counts[i];
  pack[i] = ((partial[i] + base) << 14) | cnti;
  if (cnti > 0) {
    int g = i >> 15;                 // NCELLS = 2^15
    unsigned b = (unsigned)(g >> 1);
    unsigned cellw = (unsigned)(i & (NCELLS - 1));
    unsigned nch = (cnti + QC - 1) / QC;
    unsigned task = (g & 1) ? 0u : 2u;
    unsigned slot = atomicAdd(&wcnt[4], nch);
    for (unsigned j = 0; j < nch; ++j)
      wlist[slot + j] = (b << 30) | (task << 28) | (cellw << 13) | j;
  }
}

__global__ __launch_bounds__(256) void scatter_kernel(
    const float* __restrict__ yp, const float* __restrict__ yt,
    const unsigned* __restrict__ pack, const int* __restrict__ pflat,
    const unsigned* __restrict__ prank, float4* __restrict__ sorted) {
  int t = blockIdx.x * 256 + threadIdx.x;
  const float* src;
  int row;
  if (t < NROWS) { row = t; src = yp + 3 * t; }
  else { row = t - NROWS; src = yt + 3 * row; }
  unsigned pos = (pack[pflat[t]] >> 14) + prank[t];
  sorted[pos] = make_float4(src[0], src[1], src[2], __int_as_float(row));
}

// ---------- queries: partitioned-claim waves over (cell,chunk) items -------
// Fused T items: same wave runs kNN vs P grid then vs T grid for QC queries,
// emitting per-row scalars minrow (=knnP[0]) and dens (=sum|knnP-knnT|) plus
// one exactness flag. P items: mincol (exact via per-query stop rule).
__global__ __launch_bounds__(256) void query_kernel(
    const float4* __restrict__ sorted, const unsigned* __restrict__ pack,
    unsigned* __restrict__ wcnt, const unsigned* __restrict__ wlist,
    float* __restrict__ minrow_arr, float* __restrict__ densrow,
    float* __restrict__ mincol_arr, unsigned* __restrict__ flags) {
  __shared__ unsigned sb[4][3][SEGCAP];
  __shared__ float cbw[4][64];
  __shared__ float vPw[4][QC][16];       // sqrt'd P-side top-16 stash
  const int wave = threadIdx.x >> 6, lane = threadIdx.x & 63;
  unsigned* sS = sb[wave][0];
  unsigned* sC = sb[wave][1];
  unsigned* sP = sb[wave][2];
  float* cbuf = cbw[wave];
  const unsigned nwork = wcnt[4];
  const int wid = blockIdx.x * 4 + wave;
  const unsigned part = (unsigned)(wid & (NPART - 1));
  unsigned* ctr = wcnt + 64 + part * CTRSTRIDE;    // own cacheline per counter
  for (;;) {
    unsigned tk;
    if (lane == 0) tk = atomicAdd(ctr, 1u);        // partition-local ticket
    tk = (unsigned)__shfl((int)tk, 0, 64);
    const unsigned wrk = tk * NPART + part;        // item index
    if (wrk >= nwork) break;
    const unsigned e = wlist[wrk];
    const int b = (int)((e >> 30) & 1u);
    const int task = (int)((e >> 28) & 3u);
    const int cell = (int)((e >> 13) & 32767u);
    const int qoff = (int)(e & 8191u) * QC;
    const int qg = (task == 2) ? 2 * b : 2 * b + 1;
    const unsigned pc = pack[qg * NCELLS + cell];
    const int cstart = (int)(pc >> 14);
    const int ccnt = (int)(pc & 16383u);
    const int nq = min(QC, ccnt - qoff);
    const int cx = cell & (GRID - 1), cy = (cell >> 5) & (GRID - 1), cz = cell >> 10;

    float qx[QC], qy[QC], qz[QC];
    int rowq[QC];
#pragma unroll
    for (int q = 0; q < QC; ++q) {   // duplicate last query into empty slots
      float4 eq = sorted[cstart + qoff + min(q, nq - 1)];
      qx[q] = eq.x; qy[q] = eq.y; qz[q] = eq.z;
      rowq[q] = __float_as_int(eq.w);
    }

    if (task == 0) {
      // ---- pass 1: T queries vs P grid ----
      float a[QC][KC];
      float dminq[QC];
      int cntq[QC];
      float bnd2q[QC];
      unsigned badbits = 0;
#pragma unroll
      for (int q = 0; q < QC; ++q) {
        dminq[q] = INFINITY;
#pragma unroll
        for (int k = 0; k < KC; ++k) a[q][k] = INFINITY;
      }
      wave_grid_knn_q<KC, KNN>(2 * b, cx, cy, cz, qx, qy, qz, sorted, pack,
                               sS, sC, sP, lane, a, dminq, cntq, bnd2q);
#pragma unroll
      for (int q = 0; q < QC; ++q) {
        if (q >= nq) break;                          // wave-uniform
        bool bad;
        float v = epilogue16(a[q], dminq[q], cntq[q], bnd2q[q], cbuf, lane, bad);
        if (lane < KNN) vPw[wave][q][lane] = sqrtf(v);
        if (bad) badbits |= (1u << q);
      }
      // ---- pass 2: T queries vs T grid ----
#pragma unroll
      for (int q = 0; q < QC; ++q) {
        dminq[q] = INFINITY;
#pragma unroll
        for (int k = 0; k < KC; ++k) a[q][k] = INFINITY;
      }
      wave_grid_knn_q<KC, KNN>(2 * b + 1, cx, cy, cz, qx, qy, qz, sorted, pack,
                               sS, sC, sP, lane, a, dminq, cntq, bnd2q);
#pragma unroll
      for (int q = 0; q < QC; ++q) {
        if (q >= nq) break;
        bool bad;
        float v = epilogue16(a[q], dminq[q], cntq[q], bnd2q[q], cbuf, lane, bad);
        float vp = (lane < KNN) ? vPw[wave][q][lane] : 0.0f;
        float d = (lane < KNN) ? fabsf(vp - sqrtf(v)) : 0.0f;
#pragma unroll
        for (int s2 = 1; s2 < 16; s2 <<= 1) d += __shfl_xor(d, s2, 64);
        float mr = __shfl(vp, 0, 64);                // knnP[0] from lane 0
        if (lane == 0) {
          minrow_arr[rowq[q]] = mr;
          densrow[rowq[q]] = d;
          flags[rowq[q]] = (((badbits >> q) & 1u) | (bad ? 1u : 0u));
        }
      }
    } else {
      // ---- P queries vs T grid -> mincol (exact: lane minima never lost) ----
      float a1[QC][1];
      float dminq[QC];
      int cntq[QC];
      float bnd2q[QC];
#pragma unroll
      for (int q = 0; q < QC; ++q) { a1[q][0] = INFINITY; dminq[q] = INFINITY; }
      wave_grid_knn_q<1, 1>(2 * b + 1, cx, cy, cz, qx, qy, qz, sorted, pack,
                            sS, sC, sP, lane, a1, dminq, cntq, bnd2q);
#pragma unroll
      for (int q = 0; q < QC; ++q) {
        if (q >= nq) break;
        float v = a1[q][0];
#pragma unroll
        for (int s2 = 1; s2 < 64; s2 <<= 1) v = fminf(v, __shfl_xor(v, s2, 64));
        if (lane == 0) mincol_arr[rowq[q]] = sqrtf(v);
      }
    }
  }
}

// Guaranteed-exact dense fallback over one grid slice (8192 points):
// lane r (r<16) returns the r-th smallest squared distance.
__device__ float exact16_rowlist(const float4* __restrict__ base,
                                 float qx, float qy, float qz, int lane) {
  float a[KNN];
#pragma unroll
  for (int k = 0; k < KNN; ++k) a[k] = INFINITY;
  for (int s = 0; s < NPTS / 64; ++s) {
    float d = sqd3(qx, qy, qz, base[s * 64 + lane]);
    insertK(a, d);
  }
  float res = INFINITY;
#pragma unroll 1
  for (int r = 0; r < KNN; ++r) {
    float v = a[0];
    int idx = lane;
#pragma unroll
    for (int s = 1; s < 64; s <<= 1) {
      float ov = __shfl_xor(v, s, 64);
      int oi = __shfl_xor(idx, s, 64);
      bool take = (ov < v) || (ov == v && oi < idx);
      v = take ? ov : v;
      idx = take ? oi : idx;
    }
    if (lane == r) res = v;
    if (lane == idx) {
#pragma unroll
      for (int k = 0; k < KNN - 1; ++k) a[k] = a[k + 1];
      a[KNN - 1] = INFINITY;
    }
  }
  return res;
}

// Fused tail+combine: each wave densely repairs flagged rows among its 64
// rows (expected ~0), then deterministic double partials over per-row
// scalars (block-ordered; bit-stable across runs).
__global__ __launch_bounds__(256) void combine_kernel(
    const float* __restrict__ yt, const float4* __restrict__ sorted,
    const unsigned* __restrict__ flags, float* __restrict__ minrow_arr,
    float* __restrict__ densrow, const float* __restrict__ mincol_arr,
    double* __restrict__ pd) {
  __shared__ double s1[256], s2[256], s3[256];
  const int t = threadIdx.x, lane = t & 63, wave = t >> 6;
  const int row0 = blockIdx.x * 256;
  const int rbase = row0 + wave * 64;
  unsigned f0 = flags[rbase + lane];
  unsigned long long m0 = __ballot(f0 != 0u);
  while (m0) {                                        // wave-uniform loop
    int rr = __ffsll(m0) - 1; m0 &= m0 - 1;
    int row = rbase + rr;
    int bb = row >> 13;
    const float* q = yt + 3 * row;
    float sPq = exact16_rowlist(sorted + (size_t)(2 * bb) * NPTS,
                                q[0], q[1], q[2], lane);
    float sTq = exact16_rowlist(sorted + (size_t)(2 * bb + 1) * NPTS,
                                q[0], q[1], q[2], lane);
    float vp = (lane < KNN) ? sqrtf(sPq) : 0.0f;
    float vt = (lane < KNN) ? sqrtf(sTq) : 0.0f;
    float d = fabsf(vp - vt);
#pragma unroll
    for (int s = 1; s < 16; s <<= 1) d += __shfl_xor(d, s, 64);
    float mr = __shfl(vp, 0, 64);
    if (lane == 0) { minrow_arr[row] = mr; densrow[row] = d; }
  }
  __syncthreads();  // repairs (global writes by this block) visible block-wide
  const int row = row0 + t;
  s1[t] = (double)minrow_arr[row];
  s2[t] = (double)mincol_arr[row];
  s3[t] = (double)densrow[row];
  __syncthreads();
  for (int off = 128; off > 0; off >>= 1) {
    if (t < off) { s1[t] += s1[t + off]; s2[t] += s2[t + off]; s3[t] += s3[t + off]; }
    __syncthreads();
  }
  if (t == 0) {
    pd[blockIdx.x * 3 + 0] = s1[0];
    pd[blockIdx.x * 3 + 1] = s2[0];
    pd[blockIdx.x * 3 + 2] = s3[0];
  }
}

__global__ __launch_bounds__(64) void finalize_kernel(
    const double* __restrict__ pd, float* __restrict__ out) {
  const int t = threadIdx.x;
  double a = pd[t * 3], b = pd[t * 3 + 1], c = pd[t * 3 + 2];
#pragma unroll
  for (int s = 32; s >= 1; s >>= 1) {
    a += __shfl_down(a, s, 64);
    b += __shfl_down(b, s, 64);
    c += __shfl_down(c, s, 64);
  }
  if (t == 0) {
    double shape = 0.5 * (a + b) / (double)NROWS;
    double dens = c / ((double)NROWS * KNN);
    out[0] = (float)(shape + dens);
    out[1] = (float)shape;
    out[2] = (float)dens;
  }
}

extern "C" void kernel_launch(void* const* d_in, const int* in_sizes, int n_in,
                              void* d_out, int out_size, void* d_ws, size_t ws_size,
                              hipStream_t stream) {
  (void)in_sizes; (void)n_in; (void)out_size; (void)ws_size;
  const float* yp = (const float*)d_in[0];  // y_pred [B, N, 3]
  const float* yt = (const float*)d_in[1];  // y_true [B, N, 3]
  char* w = (char*)d_ws;
  unsigned* counts  = (unsigned*)w;  w += TOTCELLS * 4;       // 512 KB
  unsigned* partial = (unsigned*)w;  w += TOTCELLS * 4;       // 512 KB
  unsigned* aux     = (unsigned*)w;  w += 512;
  unsigned* pack    = (unsigned*)w;  w += TOTCELLS * 4;       // 512 KB
  int*      pflat   = (int*)w;       w += 2 * NROWS * 4;      // 128 KB
  unsigned* prank   = (unsigned*)w;  w += 2 * NROWS * 4;      // 128 KB
  float4*   sorted  = (float4*)w;    w += 2 * NROWS * 16;     // 1 MB
  float*    minrow  = (float*)w;     w += NROWS * 4;          // 64 KB
  float*    densrow = (float*)w;     w += NROWS * 4;          // 64 KB
  float*    mincol  = (float*)w;     w += NROWS * 4;          // 64 KB
  unsigned* flags   = (unsigned*)w;  w += NROWS * 4;          // written every launch
  double*   pd      = (double*)w;    w += 64 * 3 * 8;
  unsigned* wcnt    = (unsigned*)w;  w += 4096;               // [4]=items; 64+ = claim ctrs
  unsigned* wlist   = (unsigned*)w;  w += WLCAP * 4;          // 192 KB
  float* out = (float*)d_out;

  hipMemsetAsync(counts, 0, (size_t)TOTCELLS * 4, stream);
  count_kernel<<<2 * NROWS / 256, 256, 0, stream>>>(yp, yt, counts, pflat, prank, wcnt);
  scan1_kernel<<<SCAN_BLOCKS, 1024, 0, stream>>>(counts, partial, aux);
  pack_kernel<<<SCAN_BLOCKS, 1024, 0, stream>>>(counts, partial, aux, pack, wcnt, wlist);
  scatter_kernel<<<2 * NROWS / 256, 256, 0, stream>>>(yp, yt, pack, pflat, prank, sorted);
  query_kernel<<<QBLOCKS, 256, 0, stream>>>(sorted, pack, wcnt, wlist,
                                            minrow, densrow, mincol, flags);
  combine_kernel<<<64, 256, 0, stream>>>(yt, sorted, flags, minrow, densrow,
                                         mincol, pd);
  finalize_kernel<<<1, 64, 0, stream>>>(pd, out);
}

// Round 10
// 158.133 us; speedup vs baseline: 2.2231x; 1.0283x over previous
//
#include <hip/hip_runtime.h>
#include <math.h>

#define NPTS 8192
#define NB 2
#define NROWS (NB * NPTS)
#define KNN 16
#define KC 6          // per-lane kept candidates (truncated sorted list)

// Spatial grid: 32^3 cells of width H. 4 grids: P/T x batch. g: P=2b, T=2b+1.
#define GRID 32
#define NCELLS (GRID * GRID * GRID)        // 32768
#define TOTCELLS (4 * NCELLS)              // 131072
#define H 0.35f
#define RLO (-5.6f)
#define INVH (1.0f / H)
#define SCAN_BLOCKS 128
#define SEGCAP 132                          // >= 2*64 segments per row-chunk

// QC co-celled queries share one wave's enumeration stream. T-cell items are
// FUSED (P-grid + T-grid kNN in one item, scalar outputs). Scheduling:
// PARTITIONED dynamic claims (R6 lesson: single counter = ~300us floor;
// R9 lesson: static vs partitioned-dynamic BOTH land at 52% VALUBusy ->
// scheduling is not the lever; the serial per-batch binary search
// (~6 x 120cyc LDS chain) is -> replaced by LDS index-map expansion).
#define QC 3
#define WLCAP 49152
#define QBLOCKS 2048
#define NPART 32
#define CTRSTRIDE 16      // u32s between counters = 64 B
#define MAPCAP 1024       // per-wave u16 candidate-index map (2 KB/wave)

__device__ __forceinline__ int cellof(float x) {
  int c = (int)floorf((x - RLO) * INVH);
  return min(max(c, 0), GRID - 1);
}

__device__ __forceinline__ float sqd3(float qx, float qy, float qz, float4 c) {
  float dx = qx - c.x, dy = qy - c.y, dz = qz - c.z;
  return fmaf(dx, dx, fmaf(dy, dy, dz * dz));
}

__device__ __forceinline__ int lanerank(unsigned long long mk) {
  return __builtin_amdgcn_mbcnt_hi((unsigned)(mk >> 32),
                                   __builtin_amdgcn_mbcnt_lo((unsigned)mk, 0));
}

// Guarded insert into ascending sorted-K list (per-lane).
template <int K>
__device__ __forceinline__ void insertK(float (&a)[K], float d) {
  if (d < a[K - 1]) {
    a[K - 1] = d;
#pragma unroll
    for (int k = K - 1; k > 0; --k) {
      float lo = fminf(a[k - 1], a[k]);
      a[k] = fmaxf(a[k - 1], a[k]);
      a[k - 1] = lo;
    }
  }
}

// Full ascending bitonic sort of one value per lane across the 64-lane wave.
__device__ __forceinline__ float bitonic_sort64(float v, int lane) {
#pragma unroll
  for (int k = 2; k <= 64; k <<= 1) {
#pragma unroll
    for (int j = k >> 1; j >= 1; j >>= 1) {
      float o = __shfl_xor(v, j, 64);
      bool up = ((lane & k) == 0);
      bool lower = ((lane & j) == 0);
      float mn = fminf(v, o), mx = fmaxf(v, o);
      v = (up == lower) ? mn : mx;
    }
  }
  return v;
}

// Wave-cooperative kNN for QC co-celled queries: expanding Chebyshev shells
// on the counting-sorted grid. Exactness per query q: after completing shell
// m, an unvisited point is > (m*H + fq[q]) away (fq = min per-axis in-cell
// slack, clamped >= 0). Stop when ALL QC queries have >= NEEDQ kept
// candidates within their bound. dmin[q] = min value ever not-kept (exact
// truncation test). Candidate addressing: when a row-chunk's total fits
// MAPCAP, segment runs are EXPANDED into a per-candidate u16 LDS map
// (parallel writes; same-wave LDS write->read needs no barrier, as with
// cbuf) and the scan loop prefetches next batch's map entry + point --
// removing the serial per-batch binary-search LDS chain [R9 lesson].
template <int K, int NEEDQ>
__device__ __forceinline__ void wave_grid_knn_q(
    int g, int cx, int cy, int cz,
    const float (&qx)[QC], const float (&qy)[QC], const float (&qz)[QC],
    const float4* __restrict__ sorted, const unsigned* __restrict__ pack,
    unsigned* sS, unsigned* sC, unsigned* sPre, unsigned short* smap,
    int lane, float (&a)[QC][K], float (&dminq)[QC], int (&cntq)[QC],
    float (&bnd2q)[QC]) {
  float fq[QC];
#pragma unroll
  for (int q = 0; q < QC; ++q) {
    float fx = fminf(qx[q] - (RLO + cx * H), (RLO + (cx + 1) * H) - qx[q]);
    float fy = fminf(qy[q] - (RLO + cy * H), (RLO + (cy + 1) * H) - qy[q]);
    float fz = fminf(qz[q] - (RLO + cz * H), (RLO + (cz + 1) * H) - qz[q]);
    fq[q] = fminf(fx, fminf(fy, fz));      // may be <0 for clamped queries
  }
  const int base = g * NCELLS;
  for (int m = 0; m <= GRID; ++m) {
    const int zlo = max(cz - m, 0), zhi = min(cz + m, GRID - 1);
    const int ylo = max(cy - m, 0), yhi = min(cy + m, GRID - 1);
    const int xlo = max(cx - m, 0), xhi = min(cx + m, GRID - 1);
    const int ny = yhi - ylo + 1;
    const int nrows = (zhi - zlo + 1) * ny;
    for (int rb = 0; rb < nrows; rb += 64) {
      const int rho = rb + lane;
      const bool act = rho < nrows;
      const int rr = act ? rho : 0;
      const int z = zlo + rr / ny, y = ylo + rr % ny;
      const int dza = abs(z - cz), dya = abs(y - cy);
      const bool bdry = (dza == m) || (dya == m);
      unsigned stA = 0, cnA = 0, stB = 0, cnB = 0;
      const int rowbase = base + (z * GRID + y) * GRID;
      if (act) {
        if (bdry) {  // full (clamped) x-range: contiguous segment, 2 loads
          unsigned plo = pack[rowbase + xlo];
          unsigned phi = pack[rowbase + xhi];
          stA = plo >> 14;
          cnA = ((phi >> 14) + (phi & 16383u)) - stA;
        } else {     // interior row: only the two new x = cx +- m cells
          int xl = cx - m, xr = cx + m;
          if (xl >= 0) { unsigned p = pack[rowbase + xl]; stA = p >> 14; cnA = p & 16383u; }
          if (xr < GRID) { unsigned p = pack[rowbase + xr]; stB = p >> 14; cnB = p & 16383u; }
        }
      }
      // ballot-compact nonempty segments into wave-private LDS
      unsigned long long mA = __ballot(cnA > 0);
      unsigned long long mB = __ballot(cnB > 0);
      int nA = __popcll(mA);
      int nseg = nA + __popcll(mB);
      if (nseg == 0) continue;
      int slA = lanerank(mA), slB = nA + lanerank(mB);
      if (cnA > 0) { sS[slA] = stA; sC[slA] = cnA; }
      if (cnB > 0) { sS[slB] = stB; sC[slB] = cnB; }
      // exclusive prefix over segment counts (<=128 segs, 2 halves of 64)
      unsigned total = 0;
      for (int h = 0; h < 2; ++h) {
        int sl = h * 64 + lane;
        unsigned v = (sl < nseg) ? sC[sl] : 0u;
        unsigned inc = v;
#pragma unroll
        for (int s2 = 1; s2 < 64; s2 <<= 1) {
          unsigned t = __shfl_up(inc, s2, 64);
          if (lane >= s2) inc += t;
        }
        if (sl < nseg) sPre[sl] = total + inc - v;
        total += __shfl(inc, 63, 64);
        if (nseg <= 64) break;
      }
      if (total <= (unsigned)MAPCAP) {
        // ---- map path: expand runs to per-candidate global indices ----
        // (parallel LDS writes, no serial chain; u16 ok since idx < 32768)
        for (int h2 = 0; h2 * 64 < nseg; ++h2) {
          int sl = h2 * 64 + lane;
          if (sl < nseg) {
            unsigned st = sS[sl], pre = sPre[sl], cn = sC[sl];
            for (unsigned j = 0; j < cn; ++j)
              smap[pre + j] = (unsigned short)(st + j);
          }
        }
        unsigned c0 = (unsigned)lane;
        float4 pc = sorted[smap[c0 < total ? c0 : 0]];
        for (unsigned cb = 0; cb < total; cb += 64) {
          unsigned cnx = cb + 64 + (unsigned)lane;
          float4 pn = sorted[smap[cnx < total ? cnx : 0]];  // prefetch next
          bool cact = cb + (unsigned)lane < total;
#pragma unroll
          for (int q = 0; q < QC; ++q) {
            float d = cact ? sqd3(qx[q], qy[q], qz[q], pc) : INFINITY;
            dminq[q] = fminf(dminq[q], fmaxf(d, a[q][K - 1]));
            insertK(a[q], d);
          }
          pc = pn;
        }
      } else {
        // ---- fallback: depth-adaptive binary search (rare: total>MAPCAP) --
        int sh0 = (nseg > 1) ? (1 << (31 - __clz(nseg - 1))) : 0;
        for (unsigned cb = 0; cb < total; cb += 64) {
          unsigned c = cb + (unsigned)lane;
          bool cact = c < total;
          unsigned cc = cact ? c : (total - 1);
          int lo = 0;  // max seg with sPre[seg] <= cc (sPre[0]==0)
          for (int sh = sh0; sh; sh >>= 1) {
            int mid = lo + sh;
            if (mid < nseg && sPre[mid] <= cc) lo = mid;
          }
          float4 p = sorted[sS[lo] + (cc - sPre[lo])];
#pragma unroll
          for (int q = 0; q < QC; ++q) {
            float d = cact ? sqd3(qx[q], qy[q], qz[q], p) : INFINITY;
            dminq[q] = fminf(dminq[q], fmaxf(d, a[q][K - 1]));
            insertK(a[q], d);
          }
        }
      }
    }
    // stop test: all queries have >= NEEDQ kept candidates within bound
#pragma unroll
    for (int q = 0; q < QC; ++q) {
      float bnd = fmaxf((float)m * H + fq[q], 0.0f) * 0.999f;
      bnd2q[q] = bnd * bnd;
    }
    int cpA = 0, cpB = 0;          // pack counts: q0 | q1<<16, q2
#pragma unroll
    for (int k = 0; k < K; ++k) {
      cpA += (a[0][k] <= bnd2q[0] ? 1 : 0) + (a[1][k] <= bnd2q[1] ? 65536 : 0);
      cpB += (a[2][k] <= bnd2q[2] ? 1 : 0);
    }
#pragma unroll
    for (int s2 = 1; s2 < 64; s2 <<= 1) {
      cpA += __shfl_xor(cpA, s2, 64);
      cpB += __shfl_xor(cpB, s2, 64);
    }
    cntq[0] = cpA & 0xffff;
    cntq[1] = cpA >> 16;
    cntq[2] = cpB;
    bool okall = (cntq[0] >= NEEDQ) && (cntq[1] >= NEEDQ) && (cntq[2] >= NEEDQ);
    bool covered = (zlo == 0 && zhi == GRID - 1 && ylo == 0 && yhi == GRID - 1 &&
                    xlo == 0 && xhi == GRID - 1);
    if (okall || covered) break;
  }
}

// Per-query epilogue: compact candidates <= tau, wave-sort, return ascending
// sorted value (lanes 0..15 = top-16 squared dists). bad = exactness lost.
template <int K>
__device__ __forceinline__ float epilogue16(float (&aq)[K], float dmin,
                                            int cnt, float bnd2, float* cbuf,
                                            int lane, bool& bad) {
  float tau;
  if (cnt >= KNN && cnt <= 64) {
    tau = bnd2;
  } else {
    float slm = bitonic_sort64(aq[0], lane);   // lane minima never truncated
    tau = __shfl(slm, 15, 64);
  }
  int tot = 0;
  int idxk[K];
#pragma unroll
  for (int k = 0; k < K; ++k) {
    unsigned long long mk = __ballot(aq[k] <= tau);
    idxk[k] = tot + lanerank(mk);
    tot += __popcll(mk);
  }
#pragma unroll
  for (int k = 0; k < K; ++k)
    if (aq[k] <= tau && idxk[k] < 64) cbuf[idxk[k]] = aq[k];
  float v = (lane < tot) ? cbuf[lane] : INFINITY;  // same-wave: no barrier
  v = bitonic_sort64(v, lane);
  float f15 = __shfl(v, 15, 64);
  // EXACT validity: a lost top-16 member implies dmin <= v16_true <= f15.
  bad = (tot > 64) || (__ballot(dmin <= f15) != 0ull);
  return v;
}

// ---------- build ----------
__global__ __launch_bounds__(256) void count_kernel(
    const float* __restrict__ yp, const float* __restrict__ yt,
    unsigned* __restrict__ counts, int* __restrict__ pflat,
    unsigned* __restrict__ prank, unsigned* __restrict__ wcnt) {
  if (blockIdx.x == 0) {                 // zero item count + claim counters
#pragma unroll
    for (int j = 0; j < 4; ++j) wcnt[threadIdx.x * 4 + j] = 0;  // 1024 u32
  }
  int t = blockIdx.x * 256 + threadIdx.x;          // 0 .. 2*NROWS-1
  const float* src;
  int g;
  if (t < NROWS) { src = yp + 3 * t; g = 2 * (t >> 13); }
  else { int u = t - NROWS; src = yt + 3 * u; g = 2 * (u >> 13) + 1; }
  int flat = g * NCELLS + (cellof(src[2]) * GRID + cellof(src[1])) * GRID + cellof(src[0]);
  unsigned r = atomicAdd(&counts[flat], 1u);
  pflat[t] = flat;
  prank[t] = r;
}

__global__ __launch_bounds__(1024) void scan1_kernel(
    const unsigned* __restrict__ counts, unsigned* __restrict__ partial,
    unsigned* __restrict__ aux) {
  __shared__ unsigned ws[16];
  const int t = threadIdx.x, lane = t & 63, wave = t >> 6;
  const int tid = blockIdx.x * 1024 + t;
  unsigned v = counts[tid];
  unsigned inc = v;
#pragma unroll
  for (int off = 1; off < 64; off <<= 1) {
    unsigned u = __shfl_up(inc, off, 64);
    if (lane >= off) inc += u;
  }
  if (lane == 63) ws[wave] = inc;
  __syncthreads();
  unsigned wex = 0;
  if (wave == 0) {
    unsigned o = (lane < 16) ? ws[lane] : 0u;
    unsigned wi = o;
#pragma unroll
    for (int off = 1; off < 16; off <<= 1) {
      unsigned u = __shfl_up(wi, off, 64);
      if (lane >= off) wi += u;
    }
    if (lane < 16) ws[lane] = wi - o;
  }
  __syncthreads();
  wex = ws[wave];
  partial[tid] = wex + inc - v;
  if (t == 1023) aux[blockIdx.x] = wex + inc;
}

// Fused scan2+pack + flat worklist build.
// cellinfo pack: global start (<=16b used of 18) << 14 | count (14b)
// worklist entry: b<<30 | task<<28 | cell<<13 | chunk_j
//   task 0: FUSED T-cell item (T queries vs P grid AND T grid)
//   task 2: P-cell item (P queries vs T grid -> mincol)
__global__ __launch_bounds__(1024) void pack_kernel(
    const unsigned* __restrict__ counts, const unsigned* __restrict__ partial,
    const unsigned* __restrict__ aux, unsigned* __restrict__ pack,
    unsigned* __restrict__ wcnt, unsigned* __restrict__ wlist) {
  __shared__ unsigned sa[2];
  const int t = threadIdx.x;
  if (t < 128) {
    unsigned v = (t < (int)blockIdx.x) ? aux[t] : 0u;
#pragma unroll
    for (int s = 1; s < 64; s <<= 1) v += __shfl_xor(v, s, 64);
    if ((t & 63) == 0) sa[t >> 6] = v;
  }
  __syncthreads();
  unsigned base = sa[0] + sa[1];
  int i = blockIdx.x * 1024 + t;
  unsigned cnti = counts[i];
  pack[i] = ((partial[i] + base) << 14) | cnti;
  if (cnti > 0) {
    int g = i >> 15;                 // NCELLS = 2^15
    unsigned b = (unsigned)(g >> 1);
    unsigned cellw = (unsigned)(i & (NCELLS - 1));
    unsigned nch = (cnti + QC - 1) / QC;
    unsigned task = (g & 1) ? 0u : 2u;
    unsigned slot = atomicAdd(&wcnt[4], nch);
    for (unsigned j = 0; j < nch; ++j)
      wlist[slot + j] = (b << 30) | (task << 28) | (cellw << 13) | j;
  }
}

__global__ __launch_bounds__(256) void scatter_kernel(
    const float* __restrict__ yp, const float* __restrict__ yt,
    const unsigned* __restrict__ pack, const int* __restrict__ pflat,
    const unsigned* __restrict__ prank, float4* __restrict__ sorted) {
  int t = blockIdx.x * 256 + threadIdx.x;
  const float* src;
  int row;
  if (t < NROWS) { row = t; src = yp + 3 * t; }
  else { row = t - NROWS; src = yt + 3 * row; }
  unsigned pos = (pack[pflat[t]] >> 14) + prank[t];
  sorted[pos] = make_float4(src[0], src[1], src[2], __int_as_float(row));
}

// ---------- queries: partitioned-claim waves over (cell,chunk) items -------
// Fused T items: same wave runs kNN vs P grid then vs T grid for QC queries,
// emitting per-row scalars minrow (=knnP[0]) and dens (=sum|knnP-knnT|) plus
// one exactness flag. P items: mincol (exact via per-query stop rule).
__global__ __launch_bounds__(256) void query_kernel(
    const float4* __restrict__ sorted, const unsigned* __restrict__ pack,
    unsigned* __restrict__ wcnt, const unsigned* __restrict__ wlist,
    float* __restrict__ minrow_arr, float* __restrict__ densrow,
    float* __restrict__ mincol_arr, unsigned* __restrict__ flags) {
  __shared__ unsigned sb[4][3][SEGCAP];
  __shared__ float cbw[4][64];
  __shared__ float vPw[4][QC][16];       // sqrt'd P-side top-16 stash
  __shared__ unsigned short smw[4][MAPCAP];  // candidate-index maps (8 KB)
  const int wave = threadIdx.x >> 6, lane = threadIdx.x & 63;
  unsigned* sS = sb[wave][0];
  unsigned* sC = sb[wave][1];
  unsigned* sP = sb[wave][2];
  float* cbuf = cbw[wave];
  unsigned short* smap = smw[wave];
  const unsigned nwork = wcnt[4];
  const int wid = blockIdx.x * 4 + wave;
  const unsigned part = (unsigned)(wid & (NPART - 1));
  unsigned* ctr = wcnt + 64 + part * CTRSTRIDE;    // own cacheline per counter
  for (;;) {
    unsigned tk;
    if (lane == 0) tk = atomicAdd(ctr, 1u);        // partition-local ticket
    tk = (unsigned)__shfl((int)tk, 0, 64);
    const unsigned wrk = tk * NPART + part;        // item index
    if (wrk >= nwork) break;
    const unsigned e = wlist[wrk];
    const int b = (int)((e >> 30) & 1u);
    const int task = (int)((e >> 28) & 3u);
    const int cell = (int)((e >> 13) & 32767u);
    const int qoff = (int)(e & 8191u) * QC;
    const int qg = (task == 2) ? 2 * b : 2 * b + 1;
    const unsigned pc = pack[qg * NCELLS + cell];
    const int cstart = (int)(pc >> 14);
    const int ccnt = (int)(pc & 16383u);
    const int nq = min(QC, ccnt - qoff);
    const int cx = cell & (GRID - 1), cy = (cell >> 5) & (GRID - 1), cz = cell >> 10;

    float qx[QC], qy[QC], qz[QC];
    int rowq[QC];
#pragma unroll
    for (int q = 0; q < QC; ++q) {   // duplicate last query into empty slots
      float4 eq = sorted[cstart + qoff + min(q, nq - 1)];
      qx[q] = eq.x; qy[q] = eq.y; qz[q] = eq.z;
      rowq[q] = __float_as_int(eq.w);
    }

    if (task == 0) {
      // ---- pass 1: T queries vs P grid ----
      float a[QC][KC];
      float dminq[QC];
      int cntq[QC];
      float bnd2q[QC];
      unsigned badbits = 0;
#pragma unroll
      for (int q = 0; q < QC; ++q) {
        dminq[q] = INFINITY;
#pragma unroll
        for (int k = 0; k < KC; ++k) a[q][k] = INFINITY;
      }
      wave_grid_knn_q<KC, KNN>(2 * b, cx, cy, cz, qx, qy, qz, sorted, pack,
                               sS, sC, sP, smap, lane, a, dminq, cntq, bnd2q);
#pragma unroll
      for (int q = 0; q < QC; ++q) {
        if (q >= nq) break;                          // wave-uniform
        bool bad;
        float v = epilogue16(a[q], dminq[q], cntq[q], bnd2q[q], cbuf, lane, bad);
        if (lane < KNN) vPw[wave][q][lane] = sqrtf(v);
        if (bad) badbits |= (1u << q);
      }
      // ---- pass 2: T queries vs T grid ----
#pragma unroll
      for (int q = 0; q < QC; ++q) {
        dminq[q] = INFINITY;
#pragma unroll
        for (int k = 0; k < KC; ++k) a[q][k] = INFINITY;
      }
      wave_grid_knn_q<KC, KNN>(2 * b + 1, cx, cy, cz, qx, qy, qz, sorted, pack,
                               sS, sC, sP, smap, lane, a, dminq, cntq, bnd2q);
#pragma unroll
      for (int q = 0; q < QC; ++q) {
        if (q >= nq) break;
        bool bad;
        float v = epilogue16(a[q], dminq[q], cntq[q], bnd2q[q], cbuf, lane, bad);
        float vp = (lane < KNN) ? vPw[wave][q][lane] : 0.0f;
        float d = (lane < KNN) ? fabsf(vp - sqrtf(v)) : 0.0f;
#pragma unroll
        for (int s2 = 1; s2 < 16; s2 <<= 1) d += __shfl_xor(d, s2, 64);
        float mr = __shfl(vp, 0, 64);                // knnP[0] from lane 0
        if (lane == 0) {
          minrow_arr[rowq[q]] = mr;
          densrow[rowq[q]] = d;
          flags[rowq[q]] = (((badbits >> q) & 1u) | (bad ? 1u : 0u));
        }
      }
    } else {
      // ---- P queries vs T grid -> mincol (exact: lane minima never lost) ----
      float a1[QC][1];
      float dminq[QC];
      int cntq[QC];
      float bnd2q[QC];
#pragma unroll
      for (int q = 0; q < QC; ++q) { a1[q][0] = INFINITY; dminq[q] = INFINITY; }
      wave_grid_knn_q<1, 1>(2 * b + 1, cx, cy, cz, qx, qy, qz, sorted, pack,
                            sS, sC, sP, smap, lane, a1, dminq, cntq, bnd2q);
#pragma unroll
      for (int q = 0; q < QC; ++q) {
        if (q >= nq) break;
        float v = a1[q][0];
#pragma unroll
        for (int s2 = 1; s2 < 64; s2 <<= 1) v = fminf(v, __shfl_xor(v, s2, 64));
        if (lane == 0) mincol_arr[rowq[q]] = sqrtf(v);
      }
    }
  }
}

// Guaranteed-exact dense fallback over one grid slice (8192 points):
// lane r (r<16) returns the r-th smallest squared distance.
__device__ float exact16_rowlist(const float4* __restrict__ base,
                                 float qx, float qy, float qz, int lane) {
  float a[KNN];
#pragma unroll
  for (int k = 0; k < KNN; ++k) a[k] = INFINITY;
  for (int s = 0; s < NPTS / 64; ++s) {
    float d = sqd3(qx, qy, qz, base[s * 64 + lane]);
    insertK(a, d);
  }
  float res = INFINITY;
#pragma unroll 1
  for (int r = 0; r < KNN; ++r) {
    float v = a[0];
    int idx = lane;
#pragma unroll
    for (int s = 1; s < 64; s <<= 1) {
      float ov = __shfl_xor(v, s, 64);
      int oi = __shfl_xor(idx, s, 64);
      bool take = (ov < v) || (ov == v && oi < idx);
      v = take ? ov : v;
      idx = take ? oi : idx;
    }
    if (lane == r) res = v;
    if (lane == idx) {
#pragma unroll
      for (int k = 0; k < KNN - 1; ++k) a[k] = a[k + 1];
      a[KNN - 1] = INFINITY;
    }
  }
  return res;
}

// Fused tail+combine: each wave densely repairs flagged rows among its 64
// rows (expected ~0), then deterministic double partials over per-row
// scalars (block-ordered; bit-stable across runs).
__global__ __launch_bounds__(256) void combine_kernel(
    const float* __restrict__ yt, const float4* __restrict__ sorted,
    const unsigned* __restrict__ flags, float* __restrict__ minrow_arr,
    float* __restrict__ densrow, const float* __restrict__ mincol_arr,
    double* __restrict__ pd) {
  __shared__ double s1[256], s2[256], s3[256];
  const int t = threadIdx.x, lane = t & 63, wave = t >> 6;
  const int row0 = blockIdx.x * 256;
  const int rbase = row0 + wave * 64;
  unsigned f0 = flags[rbase + lane];
  unsigned long long m0 = __ballot(f0 != 0u);
  while (m0) {                                        // wave-uniform loop
    int rr = __ffsll(m0) - 1; m0 &= m0 - 1;
    int row = rbase + rr;
    int bb = row >> 13;
    const float* q = yt + 3 * row;
    float sPq = exact16_rowlist(sorted + (size_t)(2 * bb) * NPTS,
                                q[0], q[1], q[2], lane);
    float sTq = exact16_rowlist(sorted + (size_t)(2 * bb + 1) * NPTS,
                                q[0], q[1], q[2], lane);
    float vp = (lane < KNN) ? sqrtf(sPq) : 0.0f;
    float vt = (lane < KNN) ? sqrtf(sTq) : 0.0f;
    float d = fabsf(vp - vt);
#pragma unroll
    for (int s = 1; s < 16; s <<= 1) d += __shfl_xor(d, s, 64);
    float mr = __shfl(vp, 0, 64);
    if (lane == 0) { minrow_arr[row] = mr; densrow[row] = d; }
  }
  __syncthreads();  // repairs (global writes by this block) visible block-wide
  const int row = row0 + t;
  s1[t] = (double)minrow_arr[row];
  s2[t] = (double)mincol_arr[row];
  s3[t] = (double)densrow[row];
  __syncthreads();
  for (int off = 128; off > 0; off >>= 1) {
    if (t < off) { s1[t] += s1[t + off]; s2[t] += s2[t + off]; s3[t] += s3[t + off]; }
    __syncthreads();
  }
  if (t == 0) {
    pd[blockIdx.x * 3 + 0] = s1[0];
    pd[blockIdx.x * 3 + 1] = s2[0];
    pd[blockIdx.x * 3 + 2] = s3[0];
  }
}

__global__ __launch_bounds__(64) void finalize_kernel(
    const double* __restrict__ pd, float* __restrict__ out) {
  const int t = threadIdx.x;
  double a = pd[t * 3], b = pd[t * 3 + 1], c = pd[t * 3 + 2];
#pragma unroll
  for (int s = 32; s >= 1; s >>= 1) {
    a += __shfl_down(a, s, 64);
    b += __shfl_down(b, s, 64);
    c += __shfl_down(c, s, 64);
  }
  if (t == 0) {
    double shape = 0.5 * (a + b) / (double)NROWS;
    double dens = c / ((double)NROWS * KNN);
    out[0] = (float)(shape + dens);
    out[1] = (float)shape;
    out[2] = (float)dens;
  }
}

extern "C" void kernel_launch(void* const* d_in, const int* in_sizes, int n_in,
                              void* d_out, int out_size, void* d_ws, size_t ws_size,
                              hipStream_t stream) {
  (void)in_sizes; (void)n_in; (void)out_size; (void)ws_size;
  const float* yp = (const float*)d_in[0];  // y_pred [B, N, 3]
  const float* yt = (const float*)d_in[1];  // y_true [B, N, 3]
  char* w = (char*)d_ws;
  unsigned* counts  = (unsigned*)w;  w += TOTCELLS * 4;       // 512 KB
  unsigned* partial = (unsigned*)w;  w += TOTCELLS * 4;       // 512 KB
  unsigned* aux     = (unsigned*)w;  w += 512;
  unsigned* pack    = (unsigned*)w;  w += TOTCELLS * 4;       // 512 KB
  int*      pflat   = (int*)w;       w += 2 * NROWS * 4;      // 128 KB
  unsigned* prank   = (unsigned*)w;  w += 2 * NROWS * 4;      // 128 KB
  float4*   sorted  = (float4*)w;    w += 2 * NROWS * 16;     // 1 MB
  float*    minrow  = (float*)w;     w += NROWS * 4;          // 64 KB
  float*    densrow = (float*)w;     w += NROWS * 4;          // 64 KB
  float*    mincol  = (float*)w;     w += NROWS * 4;          // 64 KB
  unsigned* flags   = (unsigned*)w;  w += NROWS * 4;          // written every launch
  double*   pd      = (double*)w;    w += 64 * 3 * 8;
  unsigned* wcnt    = (unsigned*)w;  w += 4096;               // [4]=items; 64+ = claim ctrs
  unsigned* wlist   = (unsigned*)w;  w += WLCAP * 4;          // 192 KB
  float* out = (float*)d_out;

  hipMemsetAsync(counts, 0, (size_t)TOTCELLS * 4, stream);
  count_kernel<<<2 * NROWS / 256, 256, 0, stream>>>(yp, yt, counts, pflat, prank, wcnt);
  scan1_kernel<<<SCAN_BLOCKS, 1024, 0, stream>>>(counts, partial, aux);
  pack_kernel<<<SCAN_BLOCKS, 1024, 0, stream>>>(counts, partial, aux, pack, wcnt, wlist);
  scatter_kernel<<<2 * NROWS / 256, 256, 0, stream>>>(yp, yt, pack, pflat, prank, sorted);
  query_kernel<<<QBLOCKS, 256, 0, stream>>>(sorted, pack, wcnt, wlist,
                                            minrow, densrow, mincol, flags);
  combine_kernel<<<64, 256, 0, stream>>>(yt, sorted, flags, minrow, densrow,
                                         mincol, pd);
  finalize_kernel<<<1, 64, 0, stream>>>(pd, out);
}